// Round 23
// baseline (373.589 us; speedup 1.0000x reference)
//
#include <hip/hip_runtime.h>

// PGA G(3,0,1) GeometricBilinear — R23: gbA A-halved products -> 3 waves/SIMD.
// P=16384, CIN=64, 2H=256, H=128, COUT=64, 16 blades.
//
// R22 state (133.8us): gbA 91us at 2 waves/SIMD (244 unified regs: left[16]
// 64 + prod[16] 64 + ~110 arch), ~60us latency-stall. R23: split product
// A-dimension into two passes — per half keep only left[8] (32 regs) live,
// re-stream right blades (+48 MFMAs/thr, ~2us), accumulate the persistent
// prod[16]. Peak live ~170 regs -> __launch_bounds__(256,3) = 3 waves/SIMD.
// Numerically identical (sum over (A,j) partitioned by A; right recomputed
// per half with bias re-applied consistently). gbB byte-identical to R22.

namespace {

constexpr int popc4(int v){int c=0;while(v){c+=v&1;v>>=1;}return c;}
constexpr float sgnf(int a,int b){int s=0;a>>=1;while(a){s+=popc4(a&b);a>>=1;}return (s&1)?-1.f:1.f;}

struct Tabs { float gp[16][16]; float jn[16][16]; };
constexpr Tabs mk(){
    Tabs t{};
    for(int a=0;a<16;a++)for(int b=0;b<16;b++){
        t.gp[a][b] = (a&b&1) ? 0.f : sgnf(a,b);
        if((a|b)==15){
            const int k = a&b;
            t.jn[a][b] = sgnf(a,15^a)*sgnf(b,15^b)*sgnf(15^a,15^b)*sgnf(k,15^k);
        } else t.jn[a][b] = 0.f;
    }
    return t;
}
constexpr Tabs TB = mk();
constexpr int GE[8] = {0,1,1,2,1,2,2,3};  // f32 fallback

constexpr int FOFF(int j){ return (j>>1)*6 + ((j&1)?2:0); }   // w1f frag base (R12)
constexpr int W1F_ELEMS = 16*48*512;           // 393216 (R12/R13 verified)
constexpr int W2F_ELEMS = 4*16*8*512;          // 262144 (R12/R13 verified)
constexpr long O2_BYTES = (long)1024*8*8*512*2; // 67108864: [ptile][e2][kfg][512]
constexpr int X1_STRIDE = 272;

typedef short bf16x8 __attribute__((ext_vector_type(8)));
typedef float f32x4  __attribute__((ext_vector_type(4)));

__device__ inline unsigned short f2bf(float f){
    unsigned int u = __float_as_uint(f);
    u = u + 0x7fffu + ((u >> 16) & 1u);
    return (unsigned short)(u >> 16);
}
// HW packed convert: dst = {lo: bf16(a), hi: bf16(b)}, RTNE — same as manual.
__device__ inline unsigned pack2(float a, float b){
    unsigned r;
    asm("v_cvt_pk_bf16_f32 %0, %1, %2" : "=v"(r) : "v"(a), "v"(b));
    return r;
}

} // namespace

// ---------------- prep: w1f + w2f (both R12/R13-verified packings) -----------
__global__ void prep_w(const float* __restrict__ w1, const float* __restrict__ w2,
                       unsigned short* __restrict__ w1f, unsigned short* __restrict__ w2f)
{
    int idx = blockIdx.x * 256 + threadIdx.x;
    if (idx < W1F_ELEMS) {
        const int fid = idx >> 9, r = idx & 511, l = r >> 3, m = r & 7;
        const int f = fid / 48, rem = fid - f*48;
        const int e = rem / 6, r6 = rem - e*6;
        const int odd = (r6 >= 2) ? 1 : 0;
        const int j = 2*e + odd, kf = odd ? r6 - 2 : r6;
        const int k = kf*32 + (l >> 4)*8 + m;
        const int ch = f*16 + (l & 15);
        const int g = popc4(j);
        float v;
        if (!odd) v = w1[(ch*64 + k)*9 + g];
        else      v = (k < 64) ? w1[(ch*64 + k)*9 + g + 4]
                               : w1[(ch*64 + (k - 64))*9 + g];
        w1f[idx] = f2bf(v);
    } else {
        idx -= W1F_ELEMS;
        if (idx < W2F_ELEMS) {
            const int fid = idx >> 9, r = idx & 511, l = r >> 3, m = r & 7;
            const int og = fid >> 7, rem = fid & 127;
            const int j2 = rem >> 3, kf = rem & 7;
            const int kp = kf*32 + (l >> 4)*8 + m;
            const int cc = kp >> 1, s = kp & 1;
            const int o2 = og*16 + (l & 15);
            const int g = popc4(j2);
            float v;
            if (!(j2 & 1)) v = s ? 0.f : w2[(o2*128 + cc)*9 + g];
            else           v = s ? w2[(o2*128 + cc)*9 + g]
                                 : w2[(o2*128 + cc)*9 + g + 4];
            w2f[idx] = f2bf(v);
        }
    }
}

// ================= K_A: phase1 + products (A-halved) -> out2 ================
// grid 2048 (ptile = bid>>1, st = bid&1), 256 thr (4 waves = grp 0..3).
__global__ __launch_bounds__(256, 3) void gbA(
    const float* __restrict__ x, const float* __restrict__ ref,
    const float* __restrict__ b1, const unsigned short* __restrict__ w1f,
    unsigned short* __restrict__ o2G)
{
    __shared__ __attribute__((aligned(16))) char U[34816];  // X1 [e*16+pos][272B]; then T
    __shared__ float lref[16];

    const int t  = threadIdx.x;
    const int ptile = blockIdx.x >> 1;
    const int st = blockIdx.x & 1;
    const int w  = t >> 6, l = t & 63, ln = l & 15, lh = l >> 4;
    const int p0 = ptile * 16;

    // ---- stage X1 (R18-R22 verified; pack2 = HW cvt_pk) ----
    {
        const int spos = t >> 4;
        #pragma unroll
        for (int rr = 0; rr < 2; ++rr) {
            const int i0 = (t & 15)*2 + rr*32;
            const float* gsrc = x + ((long)(p0 + spos))*1024 + i0*16;
            float4 v[8];
            #pragma unroll
            for (int a = 0; a < 8; ++a) v[a] = *(const float4*)(gsrc + a*4);
            char* base = U + spos*X1_STRIDE + i0*2;
            #pragma unroll
            for (int b = 0; b < 16; ++b) {
                const int e = b >> 1, s = b & 1;
                const float va = ((const float*)&v[b>>2])[b&3];
                const float vb = ((const float*)&v[4 + (b>>2)])[b&3];
                *(unsigned*)(base + e*16*X1_STRIDE + s*128) = pack2(va, vb);
            }
        }
        if (t < 16) lref[t] = ref[((long)(p0 + t))*16 + 15];
    }
    __syncthreads();

    const int f0 = st ? (w + 8) : w;
    const unsigned short* wL = w1f + f0*48*512 + l*8;        // lane-major frags
    const unsigned short* wR = w1f + (f0 + 4)*48*512 + l*8;

    // ---- products accumulated over two A-halves (R23) ----
    f32x4 prod[16];
    #pragma unroll
    for (int j = 0; j < 16; ++j) prod[j] = (f32x4)0.f;

    #pragma unroll
    for (int Ah = 0; Ah < 2; ++Ah) {
        // left GEMM for blades A = Ah*8 .. Ah*8+7 (R19-R22-verified math)
        f32x4 left[8];
        #pragma unroll
        for (int a = 0; a < 8; ++a) left[a] = (f32x4)0.f;
        #pragma unroll
        for (int ja = 0; ja < 8; ++ja) {
            const int j = Ah*8 + ja;
            const int e = j >> 1, nkf = (j & 1) ? 4 : 2;
            #pragma unroll
            for (int kf = 0; kf < nkf; ++kf) {
                const bf16x8 a = *(const bf16x8*)(U + (e*16 + ln)*X1_STRIDE + kf*64 + lh*16);
                const bf16x8 b = *(const bf16x8*)(wL + (FOFF(j) + kf)*512);
                left[ja] = __builtin_amdgcn_mfma_f32_16x16x32_bf16(a, b, left[ja], 0, 0, 0);
            }
        }
        if (Ah == 0) {
            const float bv = b1[f0*16 + ln];
            #pragma unroll
            for (int r = 0; r < 4; ++r) left[0][r] += bv;
        }

        // right stream (recomputed per half) + product columns for this half
        #pragma unroll
        for (int j = 0; j < 16; ++j) {
            const int e = j >> 1, nkf = (j & 1) ? 4 : 2;
            f32x4 right = (f32x4)0.f;
            #pragma unroll
            for (int kf = 0; kf < nkf; ++kf) {
                const bf16x8 a = *(const bf16x8*)(U + (e*16 + ln)*X1_STRIDE + kf*64 + lh*16);
                const bf16x8 b = *(const bf16x8*)(wR + (FOFF(j) + kf)*512);
                right = __builtin_amdgcn_mfma_f32_16x16x32_bf16(a, b, right, 0, 0, 0);
            }
            if (j == 0) {
                const float bv = b1[(f0 + 4)*16 + ln];
                #pragma unroll
                for (int r = 0; r < 4; ++r) right[r] += bv;
            }
            if (st == 0) {
                #pragma unroll
                for (int a = 0; a < 8; ++a) {
                    const int A = Ah*8 + a;
                    if (TB.gp[A][j] > 0.f)      prod[A ^ j] += left[a] * right;
                    else if (TB.gp[A][j] < 0.f) prod[A ^ j] -= left[a] * right;
                }
            } else {
                #pragma unroll
                for (int a = 0; a < 8; ++a) {
                    const int A = Ah*8 + a;
                    if (TB.jn[A][j] > 0.f)      prod[A & j] += left[a] * right;
                    else if (TB.jn[A][j] < 0.f) prod[A & j] -= left[a] * right;
                }
            }
        }
    }
    if (st == 1) {
        #pragma unroll
        for (int r = 0; r < 4; ++r) {
            const float rv = lref[lh*4 + r];
            #pragma unroll
            for (int j = 0; j < 16; ++j) prod[j][r] *= rv;
        }
    }
    __syncthreads();   // X1 reads done; U becomes T [e2*16+pos][272B rows]

    // ---- T-write (R19-R22 verified) ----
    #pragma unroll
    for (int e2 = 0; e2 < 8; ++e2)
        #pragma unroll
        for (int r = 0; r < 4; ++r)
            *(unsigned*)(U + (e2*16 + lh*4 + r)*X1_STRIDE + (w*16 + ln)*4) =
                pack2(prod[2*e2][r], prod[2*e2 + 1][r]);
    __syncthreads();

    // ---- copy-out (R20-R22 verified): frag-major o2G[ptile][e2][kfg][512] ----
    #pragma unroll
    for (int it = 0; it < 8; ++it) {
        const int c = it*256 + t;                 // 2048 x 16B chunks
        const int row = c >> 4;                   // e2*16 + pos
        const int e2 = row >> 4, pos = row & 15;
        const int cidx = c & 15;
        const float4 v = *(const float4*)(U + row*X1_STRIDE + cidx*16);
        const int kfg = st*4 + (cidx >> 2);
        const int lhh = cidx & 3;
        *(float4*)(o2G + (((long)ptile*8 + e2)*8 + kfg)*512 + lhh*128 + pos*8) = v;
    }
}

// ================= K_B: phase-2 GEMM, 2 ptiles/block (R22, passed) ===========
__global__ __launch_bounds__(256, 2) void gbB(
    const unsigned short* __restrict__ o2G, const float* __restrict__ b2,
    const unsigned short* __restrict__ w2f, float* __restrict__ out)
{
    const int t = threadIdx.x;
    const long pt0 = (long)blockIdx.x * 2;       // ptile pair
    const int w = t >> 6, l = t & 63, ln = l & 15, lh = l >> 4;

    f32x4 acc0[16], acc1[16];
    #pragma unroll
    for (int j2 = 0; j2 < 16; ++j2) { acc0[j2] = (f32x4)0.f; acc1[j2] = (f32x4)0.f; }

    #pragma unroll
    for (int j2 = 0; j2 < 16; ++j2) {
        const int e2 = j2 >> 1;
        const unsigned short* a0 = o2G + ((pt0*8 + e2)*8)*512 + l*8;
        const unsigned short* a1 = a0 + 8*8*512;            // next ptile
        const unsigned short* bb = w2f + ((w*128 + j2*8) << 9) + l*8;
        #pragma unroll
        for (int kf = 0; kf < 8; ++kf) {
            const bf16x8 b  = *(const bf16x8*)(bb + (kf << 9));
            const bf16x8 av0 = *(const bf16x8*)(a0 + kf*512);
            acc0[j2] = __builtin_amdgcn_mfma_f32_16x16x32_bf16(av0, b, acc0[j2], 0, 0, 0);
            const bf16x8 av1 = *(const bf16x8*)(a1 + kf*512);
            acc1[j2] = __builtin_amdgcn_mfma_f32_16x16x32_bf16(av1, b, acc1[j2], 0, 0, 0);
        }
    }
    {
        const float bv = b2[w*16 + ln];
        #pragma unroll
        for (int r = 0; r < 4; ++r) { acc0[0][r] += bv; acc1[0][r] += bv; }
    }
    // store (verified R12/R13/R18/R20): D col ln = o2, row lh*4+r = pos
    #pragma unroll
    for (int r = 0; r < 4; ++r) {
        float* g0 = out + (pt0*16 + lh*4 + r)*1024 + (w*16 + ln)*16;
        *(float4*)(g0)      = make_float4(acc0[0][r],  acc0[1][r],  acc0[2][r],  acc0[3][r]);
        *(float4*)(g0 + 4)  = make_float4(acc0[4][r],  acc0[5][r],  acc0[6][r],  acc0[7][r]);
        *(float4*)(g0 + 8)  = make_float4(acc0[8][r],  acc0[9][r],  acc0[10][r], acc0[11][r]);
        *(float4*)(g0 + 12) = make_float4(acc0[12][r], acc0[13][r], acc0[14][r], acc0[15][r]);
        float* g1 = g0 + 16*1024;
        *(float4*)(g1)      = make_float4(acc1[0][r],  acc1[1][r],  acc1[2][r],  acc1[3][r]);
        *(float4*)(g1 + 4)  = make_float4(acc1[4][r],  acc1[5][r],  acc1[6][r],  acc1[7][r]);
        *(float4*)(g1 + 8)  = make_float4(acc1[8][r],  acc1[9][r],  acc1[10][r], acc1[11][r]);
        *(float4*)(g1 + 12) = make_float4(acc1[12][r], acc1[13][r], acc1[14][r], acc1[15][r]);
    }
}

// ================= fp32 last-resort fallback (verified R3) ===================
__global__ __launch_bounds__(256, 1) void gb_fused_f32(
    const float* __restrict__ x, const float* __restrict__ ref,
    const float* __restrict__ w1, const float* __restrict__ b1,
    const float* __restrict__ w2, const float* __restrict__ b2,
    float* __restrict__ out)
{
    __shared__ float lds[16384];
    __shared__ float lrefs[8];
    const int t = threadIdx.x;
    const int p0 = blockIdx.x * 8;
    {
        const float4* xg = reinterpret_cast<const float4*>(x) + (size_t)p0 * 256;
        float4* xl = reinterpret_cast<float4*>(lds);
        #pragma unroll
        for (int r = 0; r < 8; ++r) xl[r*256 + t] = xg[r*256 + t];
        if (t < 8) lrefs[t] = ref[(p0 + t)*16 + 15];
    }
    __syncthreads();
    const int c    = t & 127;
    const int half = t >> 7;
    const int ca   = (c < 64) ? c : (c + 64);
    const int cb   = ca + 64;
    float acc[4][2][16];
    #pragma unroll
    for (int q = 0; q < 4; ++q)
        #pragma unroll
        for (int s = 0; s < 2; ++s)
            #pragma unroll
            for (int j = 0; j < 16; ++j) acc[q][s][j] = 0.f;
    for (int i = 0; i < 64; ++i) {
        float wa[9], wb[9];
        #pragma unroll
        for (int r = 0; r < 9; ++r) { wa[r] = w1[(ca*64+i)*9 + r]; wb[r] = w1[(cb*64+i)*9 + r]; }
        #pragma unroll
        for (int q = 0; q < 4; ++q) {
            const float* xv = lds + (half*4 + q)*1024 + i*16;
            float xr[16];
            #pragma unroll
            for (int j4 = 0; j4 < 4; ++j4) {
                const float4 v = *reinterpret_cast<const float4*>(xv + 4*j4);
                xr[4*j4+0]=v.x; xr[4*j4+1]=v.y; xr[4*j4+2]=v.z; xr[4*j4+3]=v.w;
            }
            #pragma unroll
            for (int e = 0; e < 8; ++e) {
                const int ge = GE[e];
                const float xe = xr[2*e], xo = xr[2*e+1];
                acc[q][0][2*e]   += wa[ge]   * xe;
                acc[q][0][2*e+1] += wa[ge+1] * xo;
                acc[q][0][2*e+1] += wa[ge+5] * xe;
                acc[q][1][2*e]   += wb[ge]   * xe;
                acc[q][1][2*e+1] += wb[ge+1] * xo;
                acc[q][1][2*e+1] += wb[ge+5] * xe;
            }
        }
    }
    {
        const float ba = b1[ca], bb = b1[cb];
        #pragma unroll
        for (int q = 0; q < 4; ++q) { acc[q][0][0] += ba; acc[q][1][0] += bb; }
    }
    __syncthreads();
    #pragma unroll
    for (int q = 0; q < 4; ++q) {
        float prod[16];
        #pragma unroll
        for (int j = 0; j < 16; ++j) prod[j] = 0.f;
        if (c < 64) {
            #pragma unroll
            for (int A = 0; A < 16; ++A)
                #pragma unroll
                for (int B = 0; B < 16; ++B)
                    if (TB.gp[A][B] != 0.f)
                        prod[A ^ B] += TB.gp[A][B] * acc[q][0][A] * acc[q][1][B];
        } else {
            #pragma unroll
            for (int A = 0; A < 16; ++A)
                #pragma unroll
                for (int B = 0; B < 16; ++B)
                    if (TB.jn[A][B] != 0.f)
                        prod[A & B] += TB.jn[A][B] * acc[q][0][A] * acc[q][1][B];
            const float rp = lrefs[half*4 + q];
            #pragma unroll
            for (int j = 0; j < 16; ++j) prod[j] *= rp;
        }
        const int pos = half*4 + q;
        #pragma unroll
        for (int j4 = 0; j4 < 4; ++j4)
            *reinterpret_cast<float4*>(&lds[(pos*4 + j4)*512 + c*4]) =
                make_float4(prod[4*j4], prod[4*j4+1], prod[4*j4+2], prod[4*j4+3]);
    }
    __syncthreads();
    const int o    = t & 63;
    const int slot = t >> 6;
    float oacc[2][16];
    #pragma unroll
    for (int e2 = 0; e2 < 2; ++e2)
        #pragma unroll
        for (int j = 0; j < 16; ++j) oacc[e2][j] = 0.f;
    for (int i = 0; i < 128; ++i) {
        float wv[9];
        #pragma unroll
        for (int r = 0; r < 9; ++r) wv[r] = w2[(o*128+i)*9 + r];
        #pragma unroll
        for (int e2 = 0; e2 < 2; ++e2) {
            const int pos = slot*2 + e2;
            float xr[16];
            #pragma unroll
            for (int j4 = 0; j4 < 4; ++j4) {
                const float4 v = *reinterpret_cast<const float4*>(&lds[(pos*4 + j4)*512 + i*4]);
                xr[4*j4+0]=v.x; xr[4*j4+1]=v.y; xr[4*j4+2]=v.z; xr[4*j4+3]=v.w;
            }
            #pragma unroll
            for (int e = 0; e < 8; ++e) {
                const int ge = GE[e];
                oacc[e2][2*e]   += wv[ge]   * xr[2*e];
                oacc[e2][2*e+1] += wv[ge+1] * xr[2*e+1];
                oacc[e2][2*e+1] += wv[ge+5] * xr[2*e];
            }
        }
    }
    {
        const float bo = b2[o];
        #pragma unroll
        for (int e2 = 0; e2 < 2; ++e2) {
            oacc[e2][0] += bo;
            const int pos = p0 + slot*2 + e2;
            float* og = out + (size_t)pos*1024 + o*16;
            #pragma unroll
            for (int j4 = 0; j4 < 4; ++j4)
                *reinterpret_cast<float4*>(og + 4*j4) =
                    make_float4(oacc[e2][4*j4], oacc[e2][4*j4+1],
                                oacc[e2][4*j4+2], oacc[e2][4*j4+3]);
        }
    }
}

extern "C" void kernel_launch(void* const* d_in, const int* in_sizes, int n_in,
                              void* d_out, int out_size, void* d_ws, size_t ws_size,
                              hipStream_t stream)
{
    const float* x  = (const float*)d_in[0];
    const float* rf = (const float*)d_in[1];
    const float* w1 = (const float*)d_in[2];
    const float* b1 = (const float*)d_in[3];
    const float* w2 = (const float*)d_in[4];
    const float* b2 = (const float*)d_in[5];
    float* out = (float*)d_out;

    const size_t need = O2_BYTES + (size_t)(W1F_ELEMS + W2F_ELEMS)*2;
    if (ws_size >= need) {
        unsigned short* o2G = (unsigned short*)d_ws;
        unsigned short* w1f = (unsigned short*)((char*)d_ws + O2_BYTES);
        unsigned short* w2f = w1f + W1F_ELEMS;
        prep_w<<<(W1F_ELEMS + W2F_ELEMS + 255)/256, 256, 0, stream>>>(w1, w2, w1f, w2f);
        gbA<<<2048, 256, 0, stream>>>(x, rf, b1, w1f, o2G);
        gbB<<<512, 256, 0, stream>>>(o2G, b2, w2f, out);
    } else {
        gb_fused_f32<<<2048, 256, 0, stream>>>(x, rf, w1, b1, w2, b2, out);
    }
}

// Round 24
// 134.114 us; speedup vs baseline: 2.7856x; 2.7856x over previous
//
#include <hip/hip_runtime.h>

// PGA G(3,0,1) GeometricBilinear — R24 = R22 verbatim (known best, 133.8us).
// R23's (256,3) A-halved gbA spilled (VGPR 84, WRITE 626MB, 311us) — the
// persistent prod[16] + left accumulators cannot fit a 3-wave register
// budget; reverted. gbA: 2048 blocks x 256thr, lane-major w1f frags, flipped
// MFMA, in-register products, frag-major out2. gbB: 512 blocks, 2 ptiles
// each, B-frag amortized. All layouts R19-R22 verified.

namespace {

constexpr int popc4(int v){int c=0;while(v){c+=v&1;v>>=1;}return c;}
constexpr float sgnf(int a,int b){int s=0;a>>=1;while(a){s+=popc4(a&b);a>>=1;}return (s&1)?-1.f:1.f;}

struct Tabs { float gp[16][16]; float jn[16][16]; };
constexpr Tabs mk(){
    Tabs t{};
    for(int a=0;a<16;a++)for(int b=0;b<16;b++){
        t.gp[a][b] = (a&b&1) ? 0.f : sgnf(a,b);
        if((a|b)==15){
            const int k = a&b;
            t.jn[a][b] = sgnf(a,15^a)*sgnf(b,15^b)*sgnf(15^a,15^b)*sgnf(k,15^k);
        } else t.jn[a][b] = 0.f;
    }
    return t;
}
constexpr Tabs TB = mk();
constexpr int GE[8] = {0,1,1,2,1,2,2,3};  // f32 fallback

constexpr int FOFF(int j){ return (j>>1)*6 + ((j&1)?2:0); }   // w1f frag base (R12)
constexpr int W1F_ELEMS = 16*48*512;           // 393216 (R12/R13 verified)
constexpr int W2F_ELEMS = 4*16*8*512;          // 262144 (R12/R13 verified)
constexpr long O2_BYTES = (long)1024*8*8*512*2; // 67108864: [ptile][e2][kfg][512]
constexpr int X1_STRIDE = 272;

typedef short bf16x8 __attribute__((ext_vector_type(8)));
typedef float f32x4  __attribute__((ext_vector_type(4)));

__device__ inline unsigned short f2bf(float f){
    unsigned int u = __float_as_uint(f);
    u = u + 0x7fffu + ((u >> 16) & 1u);
    return (unsigned short)(u >> 16);
}
// HW packed convert: dst = {lo: bf16(a), hi: bf16(b)}, RTNE — same as manual.
__device__ inline unsigned pack2(float a, float b){
    unsigned r;
    asm("v_cvt_pk_bf16_f32 %0, %1, %2" : "=v"(r) : "v"(a), "v"(b));
    return r;
}

} // namespace

// ---------------- prep: w1f + w2f (both R12/R13-verified packings) -----------
__global__ void prep_w(const float* __restrict__ w1, const float* __restrict__ w2,
                       unsigned short* __restrict__ w1f, unsigned short* __restrict__ w2f)
{
    int idx = blockIdx.x * 256 + threadIdx.x;
    if (idx < W1F_ELEMS) {
        const int fid = idx >> 9, r = idx & 511, l = r >> 3, m = r & 7;
        const int f = fid / 48, rem = fid - f*48;
        const int e = rem / 6, r6 = rem - e*6;
        const int odd = (r6 >= 2) ? 1 : 0;
        const int j = 2*e + odd, kf = odd ? r6 - 2 : r6;
        const int k = kf*32 + (l >> 4)*8 + m;
        const int ch = f*16 + (l & 15);
        const int g = popc4(j);
        float v;
        if (!odd) v = w1[(ch*64 + k)*9 + g];
        else      v = (k < 64) ? w1[(ch*64 + k)*9 + g + 4]
                               : w1[(ch*64 + (k - 64))*9 + g];
        w1f[idx] = f2bf(v);
    } else {
        idx -= W1F_ELEMS;
        if (idx < W2F_ELEMS) {
            const int fid = idx >> 9, r = idx & 511, l = r >> 3, m = r & 7;
            const int og = fid >> 7, rem = fid & 127;
            const int j2 = rem >> 3, kf = rem & 7;
            const int kp = kf*32 + (l >> 4)*8 + m;
            const int cc = kp >> 1, s = kp & 1;
            const int o2 = og*16 + (l & 15);
            const int g = popc4(j2);
            float v;
            if (!(j2 & 1)) v = s ? 0.f : w2[(o2*128 + cc)*9 + g];
            else           v = s ? w2[(o2*128 + cc)*9 + g]
                                 : w2[(o2*128 + cc)*9 + g + 4];
            w2f[idx] = f2bf(v);
        }
    }
}

// ================= K_A: phase1 + products -> out2 (R21/R22 verified) =========
// grid 2048 (ptile = bid>>1, st = bid&1), 256 thr (4 waves = grp 0..3).
__global__ __launch_bounds__(256, 2) void gbA(
    const float* __restrict__ x, const float* __restrict__ ref,
    const float* __restrict__ b1, const unsigned short* __restrict__ w1f,
    unsigned short* __restrict__ o2G)
{
    __shared__ __attribute__((aligned(16))) char U[34816];  // X1 [e*16+pos][272B]; then T
    __shared__ float lref[16];

    const int t  = threadIdx.x;
    const int ptile = blockIdx.x >> 1;
    const int st = blockIdx.x & 1;
    const int w  = t >> 6, l = t & 63, ln = l & 15, lh = l >> 4;
    const int p0 = ptile * 16;

    // ---- stage X1 (R18-R22 verified; pack2 = HW cvt_pk) ----
    {
        const int spos = t >> 4;
        #pragma unroll
        for (int rr = 0; rr < 2; ++rr) {
            const int i0 = (t & 15)*2 + rr*32;
            const float* gsrc = x + ((long)(p0 + spos))*1024 + i0*16;
            float4 v[8];
            #pragma unroll
            for (int a = 0; a < 8; ++a) v[a] = *(const float4*)(gsrc + a*4);
            char* base = U + spos*X1_STRIDE + i0*2;
            #pragma unroll
            for (int b = 0; b < 16; ++b) {
                const int e = b >> 1, s = b & 1;
                const float va = ((const float*)&v[b>>2])[b&3];
                const float vb = ((const float*)&v[4 + (b>>2)])[b&3];
                *(unsigned*)(base + e*16*X1_STRIDE + s*128) = pack2(va, vb);
            }
        }
        if (t < 16) lref[t] = ref[((long)(p0 + t))*16 + 15];
    }
    __syncthreads();

    const int f0 = st ? (w + 8) : w;
    const unsigned short* wL = w1f + f0*48*512 + l*8;        // lane-major frags
    const unsigned short* wR = w1f + (f0 + 4)*48*512 + l*8;

    // ---- left GEMM (R19-R22 verified flipped orientation) ----
    f32x4 left[16];
    #pragma unroll
    for (int j = 0; j < 16; ++j) left[j] = (f32x4)0.f;
    #pragma unroll
    for (int j = 0; j < 16; ++j) {
        const int e = j >> 1, nkf = (j & 1) ? 4 : 2;
        #pragma unroll
        for (int kf = 0; kf < nkf; ++kf) {
            const bf16x8 a = *(const bf16x8*)(U + (e*16 + ln)*X1_STRIDE + kf*64 + lh*16);
            const bf16x8 b = *(const bf16x8*)(wL + (FOFF(j) + kf)*512);
            left[j] = __builtin_amdgcn_mfma_f32_16x16x32_bf16(a, b, left[j], 0, 0, 0);
        }
    }
    {
        const float bv = b1[f0*16 + ln];
        #pragma unroll
        for (int r = 0; r < 4; ++r) left[0][r] += bv;
    }

    // ---- right stream + products (R19-R22 verified) ----
    f32x4 prod[16];
    #pragma unroll
    for (int j = 0; j < 16; ++j) prod[j] = (f32x4)0.f;
    #pragma unroll
    for (int j = 0; j < 16; ++j) {
        const int e = j >> 1, nkf = (j & 1) ? 4 : 2;
        f32x4 right = (f32x4)0.f;
        #pragma unroll
        for (int kf = 0; kf < nkf; ++kf) {
            const bf16x8 a = *(const bf16x8*)(U + (e*16 + ln)*X1_STRIDE + kf*64 + lh*16);
            const bf16x8 b = *(const bf16x8*)(wR + (FOFF(j) + kf)*512);
            right = __builtin_amdgcn_mfma_f32_16x16x32_bf16(a, b, right, 0, 0, 0);
        }
        if (j == 0) {
            const float bv = b1[(f0 + 4)*16 + ln];
            #pragma unroll
            for (int r = 0; r < 4; ++r) right[r] += bv;
        }
        if (st == 0) {
            #pragma unroll
            for (int A = 0; A < 16; ++A) {
                if (TB.gp[A][j] > 0.f)      prod[A ^ j] += left[A] * right;
                else if (TB.gp[A][j] < 0.f) prod[A ^ j] -= left[A] * right;
            }
        } else {
            #pragma unroll
            for (int A = 0; A < 16; ++A) {
                if (TB.jn[A][j] > 0.f)      prod[A & j] += left[A] * right;
                else if (TB.jn[A][j] < 0.f) prod[A & j] -= left[A] * right;
            }
        }
    }
    if (st == 1) {
        #pragma unroll
        for (int r = 0; r < 4; ++r) {
            const float rv = lref[lh*4 + r];
            #pragma unroll
            for (int j = 0; j < 16; ++j) prod[j][r] *= rv;
        }
    }
    __syncthreads();   // X1 reads done; U becomes T [e2*16+pos][272B rows]

    // ---- T-write (R19-R22 verified) ----
    #pragma unroll
    for (int e2 = 0; e2 < 8; ++e2)
        #pragma unroll
        for (int r = 0; r < 4; ++r)
            *(unsigned*)(U + (e2*16 + lh*4 + r)*X1_STRIDE + (w*16 + ln)*4) =
                pack2(prod[2*e2][r], prod[2*e2 + 1][r]);
    __syncthreads();

    // ---- copy-out (R20-R22 verified): frag-major o2G[ptile][e2][kfg][512] ----
    #pragma unroll
    for (int it = 0; it < 8; ++it) {
        const int c = it*256 + t;                 // 2048 x 16B chunks
        const int row = c >> 4;                   // e2*16 + pos
        const int e2 = row >> 4, pos = row & 15;
        const int cidx = c & 15;
        const float4 v = *(const float4*)(U + row*X1_STRIDE + cidx*16);
        const int kfg = st*4 + (cidx >> 2);
        const int lhh = cidx & 3;
        *(float4*)(o2G + (((long)ptile*8 + e2)*8 + kfg)*512 + lhh*128 + pos*8) = v;
    }
}

// ================= K_B: phase-2 GEMM, 2 ptiles/block (R22, passed) ===========
__global__ __launch_bounds__(256, 2) void gbB(
    const unsigned short* __restrict__ o2G, const float* __restrict__ b2,
    const unsigned short* __restrict__ w2f, float* __restrict__ out)
{
    const int t = threadIdx.x;
    const long pt0 = (long)blockIdx.x * 2;       // ptile pair
    const int w = t >> 6, l = t & 63, ln = l & 15, lh = l >> 4;

    f32x4 acc0[16], acc1[16];
    #pragma unroll
    for (int j2 = 0; j2 < 16; ++j2) { acc0[j2] = (f32x4)0.f; acc1[j2] = (f32x4)0.f; }

    #pragma unroll
    for (int j2 = 0; j2 < 16; ++j2) {
        const int e2 = j2 >> 1;
        const unsigned short* a0 = o2G + ((pt0*8 + e2)*8)*512 + l*8;
        const unsigned short* a1 = a0 + 8*8*512;            // next ptile
        const unsigned short* bb = w2f + ((w*128 + j2*8) << 9) + l*8;
        #pragma unroll
        for (int kf = 0; kf < 8; ++kf) {
            const bf16x8 b  = *(const bf16x8*)(bb + (kf << 9));
            const bf16x8 av0 = *(const bf16x8*)(a0 + kf*512);
            acc0[j2] = __builtin_amdgcn_mfma_f32_16x16x32_bf16(av0, b, acc0[j2], 0, 0, 0);
            const bf16x8 av1 = *(const bf16x8*)(a1 + kf*512);
            acc1[j2] = __builtin_amdgcn_mfma_f32_16x16x32_bf16(av1, b, acc1[j2], 0, 0, 0);
        }
    }
    {
        const float bv = b2[w*16 + ln];
        #pragma unroll
        for (int r = 0; r < 4; ++r) { acc0[0][r] += bv; acc1[0][r] += bv; }
    }
    // store (verified R12/R13/R18/R20): D col ln = o2, row lh*4+r = pos
    #pragma unroll
    for (int r = 0; r < 4; ++r) {
        float* g0 = out + (pt0*16 + lh*4 + r)*1024 + (w*16 + ln)*16;
        *(float4*)(g0)      = make_float4(acc0[0][r],  acc0[1][r],  acc0[2][r],  acc0[3][r]);
        *(float4*)(g0 + 4)  = make_float4(acc0[4][r],  acc0[5][r],  acc0[6][r],  acc0[7][r]);
        *(float4*)(g0 + 8)  = make_float4(acc0[8][r],  acc0[9][r],  acc0[10][r], acc0[11][r]);
        *(float4*)(g0 + 12) = make_float4(acc0[12][r], acc0[13][r], acc0[14][r], acc0[15][r]);
        float* g1 = g0 + 16*1024;
        *(float4*)(g1)      = make_float4(acc1[0][r],  acc1[1][r],  acc1[2][r],  acc1[3][r]);
        *(float4*)(g1 + 4)  = make_float4(acc1[4][r],  acc1[5][r],  acc1[6][r],  acc1[7][r]);
        *(float4*)(g1 + 8)  = make_float4(acc1[8][r],  acc1[9][r],  acc1[10][r], acc1[11][r]);
        *(float4*)(g1 + 12) = make_float4(acc1[12][r], acc1[13][r], acc1[14][r], acc1[15][r]);
    }
}

// ================= fp32 last-resort fallback (verified R3) ===================
__global__ __launch_bounds__(256, 1) void gb_fused_f32(
    const float* __restrict__ x, const float* __restrict__ ref,
    const float* __restrict__ w1, const float* __restrict__ b1,
    const float* __restrict__ w2, const float* __restrict__ b2,
    float* __restrict__ out)
{
    __shared__ float lds[16384];
    __shared__ float lrefs[8];
    const int t = threadIdx.x;
    const int p0 = blockIdx.x * 8;
    {
        const float4* xg = reinterpret_cast<const float4*>(x) + (size_t)p0 * 256;
        float4* xl = reinterpret_cast<float4*>(lds);
        #pragma unroll
        for (int r = 0; r < 8; ++r) xl[r*256 + t] = xg[r*256 + t];
        if (t < 8) lrefs[t] = ref[(p0 + t)*16 + 15];
    }
    __syncthreads();
    const int c    = t & 127;
    const int half = t >> 7;
    const int ca   = (c < 64) ? c : (c + 64);
    const int cb   = ca + 64;
    float acc[4][2][16];
    #pragma unroll
    for (int q = 0; q < 4; ++q)
        #pragma unroll
        for (int s = 0; s < 2; ++s)
            #pragma unroll
            for (int j = 0; j < 16; ++j) acc[q][s][j] = 0.f;
    for (int i = 0; i < 64; ++i) {
        float wa[9], wb[9];
        #pragma unroll
        for (int r = 0; r < 9; ++r) { wa[r] = w1[(ca*64+i)*9 + r]; wb[r] = w1[(cb*64+i)*9 + r]; }
        #pragma unroll
        for (int q = 0; q < 4; ++q) {
            const float* xv = lds + (half*4 + q)*1024 + i*16;
            float xr[16];
            #pragma unroll
            for (int j4 = 0; j4 < 4; ++j4) {
                const float4 v = *reinterpret_cast<const float4*>(xv + 4*j4);
                xr[4*j4+0]=v.x; xr[4*j4+1]=v.y; xr[4*j4+2]=v.z; xr[4*j4+3]=v.w;
            }
            #pragma unroll
            for (int e = 0; e < 8; ++e) {
                const int ge = GE[e];
                const float xe = xr[2*e], xo = xr[2*e+1];
                acc[q][0][2*e]   += wa[ge]   * xe;
                acc[q][0][2*e+1] += wa[ge+1] * xo;
                acc[q][0][2*e+1] += wa[ge+5] * xe;
                acc[q][1][2*e]   += wb[ge]   * xe;
                acc[q][1][2*e+1] += wb[ge+1] * xo;
                acc[q][1][2*e+1] += wb[ge+5] * xe;
            }
        }
    }
    {
        const float ba = b1[ca], bb = b1[cb];
        #pragma unroll
        for (int q = 0; q < 4; ++q) { acc[q][0][0] += ba; acc[q][1][0] += bb; }
    }
    __syncthreads();
    #pragma unroll
    for (int q = 0; q < 4; ++q) {
        float prod[16];
        #pragma unroll
        for (int j = 0; j < 16; ++j) prod[j] = 0.f;
        if (c < 64) {
            #pragma unroll
            for (int A = 0; A < 16; ++A)
                #pragma unroll
                for (int B = 0; B < 16; ++B)
                    if (TB.gp[A][B] != 0.f)
                        prod[A ^ B] += TB.gp[A][B] * acc[q][0][A] * acc[q][1][B];
        } else {
            #pragma unroll
            for (int A = 0; A < 16; ++A)
                #pragma unroll
                for (int B = 0; B < 16; ++B)
                    if (TB.jn[A][B] != 0.f)
                        prod[A & B] += TB.jn[A][B] * acc[q][0][A] * acc[q][1][B];
            const float rp = lrefs[half*4 + q];
            #pragma unroll
            for (int j = 0; j < 16; ++j) prod[j] *= rp;
        }
        const int pos = half*4 + q;
        #pragma unroll
        for (int j4 = 0; j4 < 4; ++j4)
            *reinterpret_cast<float4*>(&lds[(pos*4 + j4)*512 + c*4]) =
                make_float4(prod[4*j4], prod[4*j4+1], prod[4*j4+2], prod[4*j4+3]);
    }
    __syncthreads();
    const int o    = t & 63;
    const int slot = t >> 6;
    float oacc[2][16];
    #pragma unroll
    for (int e2 = 0; e2 < 2; ++e2)
        #pragma unroll
        for (int j = 0; j < 16; ++j) oacc[e2][j] = 0.f;
    for (int i = 0; i < 128; ++i) {
        float wv[9];
        #pragma unroll
        for (int r = 0; r < 9; ++r) wv[r] = w2[(o*128+i)*9 + r];
        #pragma unroll
        for (int e2 = 0; e2 < 2; ++e2) {
            const int pos = slot*2 + e2;
            float xr[16];
            #pragma unroll
            for (int j4 = 0; j4 < 4; ++j4) {
                const float4 v = *reinterpret_cast<const float4*>(&lds[(pos*4 + j4)*512 + i*4]);
                xr[4*j4+0]=v.x; xr[4*j4+1]=v.y; xr[4*j4+2]=v.z; xr[4*j4+3]=v.w;
            }
            #pragma unroll
            for (int e = 0; e < 8; ++e) {
                const int ge = GE[e];
                oacc[e2][2*e]   += wv[ge]   * xr[2*e];
                oacc[e2][2*e+1] += wv[ge+1] * xr[2*e+1];
                oacc[e2][2*e+1] += wv[ge+5] * xr[2*e];
            }
        }
    }
    {
        const float bo = b2[o];
        #pragma unroll
        for (int e2 = 0; e2 < 2; ++e2) {
            oacc[e2][0] += bo;
            const int pos = p0 + slot*2 + e2;
            float* og = out + (size_t)pos*1024 + o*16;
            #pragma unroll
            for (int j4 = 0; j4 < 4; ++j4)
                *reinterpret_cast<float4*>(og + 4*j4) =
                    make_float4(oacc[e2][4*j4], oacc[e2][4*j4+1],
                                oacc[e2][4*j4+2], oacc[e2][4*j4+3]);
        }
    }
}

extern "C" void kernel_launch(void* const* d_in, const int* in_sizes, int n_in,
                              void* d_out, int out_size, void* d_ws, size_t ws_size,
                              hipStream_t stream)
{
    const float* x  = (const float*)d_in[0];
    const float* rf = (const float*)d_in[1];
    const float* w1 = (const float*)d_in[2];
    const float* b1 = (const float*)d_in[3];
    const float* w2 = (const float*)d_in[4];
    const float* b2 = (const float*)d_in[5];
    float* out = (float*)d_out;

    const size_t need = O2_BYTES + (size_t)(W1F_ELEMS + W2F_ELEMS)*2;
    if (ws_size >= need) {
        unsigned short* o2G = (unsigned short*)d_ws;
        unsigned short* w1f = (unsigned short*)((char*)d_ws + O2_BYTES);
        unsigned short* w2f = w1f + W1F_ELEMS;
        prep_w<<<(W1F_ELEMS + W2F_ELEMS + 255)/256, 256, 0, stream>>>(w1, w2, w1f, w2f);
        gbA<<<2048, 256, 0, stream>>>(x, rf, b1, w1f, o2G);
        gbB<<<512, 256, 0, stream>>>(o2G, b2, w2f, out);
    } else {
        gb_fused_f32<<<2048, 256, 0, stream>>>(x, rf, w1, b1, w2, b2, out);
    }
}

// Round 25
// 130.736 us; speedup vs baseline: 2.8576x; 1.0258x over previous
//
#include <hip/hip_runtime.h>

// PGA G(3,0,1) GeometricBilinear — R25: gbA stages X1 once, st looped.
// P=16384, CIN=64, 2H=256, H=128, COUT=64, 16 blades.
//
// R24 (=R22) state: 134us; gbA 91us at its register-structural 2-waves/SIMD
// plateau. Remaining waste: every X1 tile staged TWICE (st=0/st=1 in separate
// blocks). R25: gbA grid 1024 (one block per ptile), st in-kernel loop reusing
// the staged X1. T gets its own buffer (X1 34.8KB + T 34.8KB = 69.6KB LDS;
// 2 blocks/CU still fits 160KB/CU). Compute/T-write/copy-out are the
// R19-R22-verified text with st as a loop variable. gbB byte-identical R22.

namespace {

constexpr int popc4(int v){int c=0;while(v){c+=v&1;v>>=1;}return c;}
constexpr float sgnf(int a,int b){int s=0;a>>=1;while(a){s+=popc4(a&b);a>>=1;}return (s&1)?-1.f:1.f;}

struct Tabs { float gp[16][16]; float jn[16][16]; };
constexpr Tabs mk(){
    Tabs t{};
    for(int a=0;a<16;a++)for(int b=0;b<16;b++){
        t.gp[a][b] = (a&b&1) ? 0.f : sgnf(a,b);
        if((a|b)==15){
            const int k = a&b;
            t.jn[a][b] = sgnf(a,15^a)*sgnf(b,15^b)*sgnf(15^a,15^b)*sgnf(k,15^k);
        } else t.jn[a][b] = 0.f;
    }
    return t;
}
constexpr Tabs TB = mk();
constexpr int GE[8] = {0,1,1,2,1,2,2,3};  // f32 fallback

constexpr int FOFF(int j){ return (j>>1)*6 + ((j&1)?2:0); }   // w1f frag base (R12)
constexpr int W1F_ELEMS = 16*48*512;           // 393216 (R12/R13 verified)
constexpr int W2F_ELEMS = 4*16*8*512;          // 262144 (R12/R13 verified)
constexpr long O2_BYTES = (long)1024*8*8*512*2; // 67108864: [ptile][e2][kfg][512]
constexpr int X1_STRIDE = 272;
constexpr int TOFF = 34816;                    // T buffer offset in U

typedef short bf16x8 __attribute__((ext_vector_type(8)));
typedef float f32x4  __attribute__((ext_vector_type(4)));

__device__ inline unsigned short f2bf(float f){
    unsigned int u = __float_as_uint(f);
    u = u + 0x7fffu + ((u >> 16) & 1u);
    return (unsigned short)(u >> 16);
}
// HW packed convert: dst = {lo: bf16(a), hi: bf16(b)}, RTNE — same as manual.
__device__ inline unsigned pack2(float a, float b){
    unsigned r;
    asm("v_cvt_pk_bf16_f32 %0, %1, %2" : "=v"(r) : "v"(a), "v"(b));
    return r;
}

} // namespace

// ---------------- prep: w1f + w2f (both R12/R13-verified packings) -----------
__global__ void prep_w(const float* __restrict__ w1, const float* __restrict__ w2,
                       unsigned short* __restrict__ w1f, unsigned short* __restrict__ w2f)
{
    int idx = blockIdx.x * 256 + threadIdx.x;
    if (idx < W1F_ELEMS) {
        const int fid = idx >> 9, r = idx & 511, l = r >> 3, m = r & 7;
        const int f = fid / 48, rem = fid - f*48;
        const int e = rem / 6, r6 = rem - e*6;
        const int odd = (r6 >= 2) ? 1 : 0;
        const int j = 2*e + odd, kf = odd ? r6 - 2 : r6;
        const int k = kf*32 + (l >> 4)*8 + m;
        const int ch = f*16 + (l & 15);
        const int g = popc4(j);
        float v;
        if (!odd) v = w1[(ch*64 + k)*9 + g];
        else      v = (k < 64) ? w1[(ch*64 + k)*9 + g + 4]
                               : w1[(ch*64 + (k - 64))*9 + g];
        w1f[idx] = f2bf(v);
    } else {
        idx -= W1F_ELEMS;
        if (idx < W2F_ELEMS) {
            const int fid = idx >> 9, r = idx & 511, l = r >> 3, m = r & 7;
            const int og = fid >> 7, rem = fid & 127;
            const int j2 = rem >> 3, kf = rem & 7;
            const int kp = kf*32 + (l >> 4)*8 + m;
            const int cc = kp >> 1, s = kp & 1;
            const int o2 = og*16 + (l & 15);
            const int g = popc4(j2);
            float v;
            if (!(j2 & 1)) v = s ? 0.f : w2[(o2*128 + cc)*9 + g];
            else           v = s ? w2[(o2*128 + cc)*9 + g]
                                 : w2[(o2*128 + cc)*9 + g + 4];
            w2f[idx] = f2bf(v);
        }
    }
}

// ================= K_A: phase1 + products -> out2 (st looped, R25) ===========
// grid 1024 (ptile), 256 thr (4 waves = grp 0..3).
__global__ __launch_bounds__(256, 2) void gbA(
    const float* __restrict__ x, const float* __restrict__ ref,
    const float* __restrict__ b1, const unsigned short* __restrict__ w1f,
    unsigned short* __restrict__ o2G)
{
    __shared__ __attribute__((aligned(16))) char U[69632];  // X1 @0 (34816), T @34816
    __shared__ float lref[16];

    const int t  = threadIdx.x;
    const int ptile = blockIdx.x;
    const int w  = t >> 6, l = t & 63, ln = l & 15, lh = l >> 4;
    const int p0 = ptile * 16;

    // ---- stage X1 ONCE (R18-R22 verified; pack2 = HW cvt_pk) ----
    {
        const int spos = t >> 4;
        #pragma unroll
        for (int rr = 0; rr < 2; ++rr) {
            const int i0 = (t & 15)*2 + rr*32;
            const float* gsrc = x + ((long)(p0 + spos))*1024 + i0*16;
            float4 v[8];
            #pragma unroll
            for (int a = 0; a < 8; ++a) v[a] = *(const float4*)(gsrc + a*4);
            char* base = U + spos*X1_STRIDE + i0*2;
            #pragma unroll
            for (int b = 0; b < 16; ++b) {
                const int e = b >> 1, s = b & 1;
                const float va = ((const float*)&v[b>>2])[b&3];
                const float vb = ((const float*)&v[4 + (b>>2)])[b&3];
                *(unsigned*)(base + e*16*X1_STRIDE + s*128) = pack2(va, vb);
            }
        }
        if (t < 16) lref[t] = ref[((long)(p0 + t))*16 + 15];
    }
    __syncthreads();

    #pragma unroll 1
    for (int st = 0; st < 2; ++st) {
        const int f0 = st ? (w + 8) : w;
        const unsigned short* wL = w1f + f0*48*512 + l*8;        // lane-major frags
        const unsigned short* wR = w1f + (f0 + 4)*48*512 + l*8;

        // ---- left GEMM (R19-R22 verified flipped orientation) ----
        f32x4 left[16];
        #pragma unroll
        for (int j = 0; j < 16; ++j) left[j] = (f32x4)0.f;
        #pragma unroll
        for (int j = 0; j < 16; ++j) {
            const int e = j >> 1, nkf = (j & 1) ? 4 : 2;
            #pragma unroll
            for (int kf = 0; kf < nkf; ++kf) {
                const bf16x8 a = *(const bf16x8*)(U + (e*16 + ln)*X1_STRIDE + kf*64 + lh*16);
                const bf16x8 b = *(const bf16x8*)(wL + (FOFF(j) + kf)*512);
                left[j] = __builtin_amdgcn_mfma_f32_16x16x32_bf16(a, b, left[j], 0, 0, 0);
            }
        }
        {
            const float bv = b1[f0*16 + ln];
            #pragma unroll
            for (int r = 0; r < 4; ++r) left[0][r] += bv;
        }

        // ---- right stream + products (R19-R22 verified) ----
        f32x4 prod[16];
        #pragma unroll
        for (int j = 0; j < 16; ++j) prod[j] = (f32x4)0.f;
        #pragma unroll
        for (int j = 0; j < 16; ++j) {
            const int e = j >> 1, nkf = (j & 1) ? 4 : 2;
            f32x4 right = (f32x4)0.f;
            #pragma unroll
            for (int kf = 0; kf < nkf; ++kf) {
                const bf16x8 a = *(const bf16x8*)(U + (e*16 + ln)*X1_STRIDE + kf*64 + lh*16);
                const bf16x8 b = *(const bf16x8*)(wR + (FOFF(j) + kf)*512);
                right = __builtin_amdgcn_mfma_f32_16x16x32_bf16(a, b, right, 0, 0, 0);
            }
            if (j == 0) {
                const float bv = b1[(f0 + 4)*16 + ln];
                #pragma unroll
                for (int r = 0; r < 4; ++r) right[r] += bv;
            }
            if (st == 0) {
                #pragma unroll
                for (int A = 0; A < 16; ++A) {
                    if (TB.gp[A][j] > 0.f)      prod[A ^ j] += left[A] * right;
                    else if (TB.gp[A][j] < 0.f) prod[A ^ j] -= left[A] * right;
                }
            } else {
                #pragma unroll
                for (int A = 0; A < 16; ++A) {
                    if (TB.jn[A][j] > 0.f)      prod[A & j] += left[A] * right;
                    else if (TB.jn[A][j] < 0.f) prod[A & j] -= left[A] * right;
                }
            }
        }
        if (st == 1) {
            #pragma unroll
            for (int r = 0; r < 4; ++r) {
                const float rv = lref[lh*4 + r];
                #pragma unroll
                for (int j = 0; j < 16; ++j) prod[j][r] *= rv;
            }
        }

        // ---- T-write (R19-R22 verified layout, T at U+TOFF) ----
        #pragma unroll
        for (int e2 = 0; e2 < 8; ++e2)
            #pragma unroll
            for (int r = 0; r < 4; ++r)
                *(unsigned*)(U + TOFF + (e2*16 + lh*4 + r)*X1_STRIDE + (w*16 + ln)*4) =
                    pack2(prod[2*e2][r], prod[2*e2 + 1][r]);
        __syncthreads();   // T visible to all waves

        // ---- copy-out (R20-R22 verified): frag-major o2G[ptile][e2][kfg][512] --
        #pragma unroll
        for (int it = 0; it < 8; ++it) {
            const int c = it*256 + t;                 // 2048 x 16B chunks
            const int row = c >> 4;                   // e2*16 + pos
            const int e2 = row >> 4, pos = row & 15;
            const int cidx = c & 15;
            const float4 v = *(const float4*)(U + TOFF + row*X1_STRIDE + cidx*16);
            const int kfg = st*4 + (cidx >> 2);
            const int lhh = cidx & 3;
            *(float4*)(o2G + (((long)ptile*8 + e2)*8 + kfg)*512 + lhh*128 + pos*8) = v;
        }
        __syncthreads();   // T reads done before next st overwrites
    }
}

// ================= K_B: phase-2 GEMM, 2 ptiles/block (R22, passed) ===========
__global__ __launch_bounds__(256, 2) void gbB(
    const unsigned short* __restrict__ o2G, const float* __restrict__ b2,
    const unsigned short* __restrict__ w2f, float* __restrict__ out)
{
    const int t = threadIdx.x;
    const long pt0 = (long)blockIdx.x * 2;       // ptile pair
    const int w = t >> 6, l = t & 63, ln = l & 15, lh = l >> 4;

    f32x4 acc0[16], acc1[16];
    #pragma unroll
    for (int j2 = 0; j2 < 16; ++j2) { acc0[j2] = (f32x4)0.f; acc1[j2] = (f32x4)0.f; }

    #pragma unroll
    for (int j2 = 0; j2 < 16; ++j2) {
        const int e2 = j2 >> 1;
        const unsigned short* a0 = o2G + ((pt0*8 + e2)*8)*512 + l*8;
        const unsigned short* a1 = a0 + 8*8*512;            // next ptile
        const unsigned short* bb = w2f + ((w*128 + j2*8) << 9) + l*8;
        #pragma unroll
        for (int kf = 0; kf < 8; ++kf) {
            const bf16x8 b  = *(const bf16x8*)(bb + (kf << 9));
            const bf16x8 av0 = *(const bf16x8*)(a0 + kf*512);
            acc0[j2] = __builtin_amdgcn_mfma_f32_16x16x32_bf16(av0, b, acc0[j2], 0, 0, 0);
            const bf16x8 av1 = *(const bf16x8*)(a1 + kf*512);
            acc1[j2] = __builtin_amdgcn_mfma_f32_16x16x32_bf16(av1, b, acc1[j2], 0, 0, 0);
        }
    }
    {
        const float bv = b2[w*16 + ln];
        #pragma unroll
        for (int r = 0; r < 4; ++r) { acc0[0][r] += bv; acc1[0][r] += bv; }
    }
    // store (verified R12/R13/R18/R20): D col ln = o2, row lh*4+r = pos
    #pragma unroll
    for (int r = 0; r < 4; ++r) {
        float* g0 = out + (pt0*16 + lh*4 + r)*1024 + (w*16 + ln)*16;
        *(float4*)(g0)      = make_float4(acc0[0][r],  acc0[1][r],  acc0[2][r],  acc0[3][r]);
        *(float4*)(g0 + 4)  = make_float4(acc0[4][r],  acc0[5][r],  acc0[6][r],  acc0[7][r]);
        *(float4*)(g0 + 8)  = make_float4(acc0[8][r],  acc0[9][r],  acc0[10][r], acc0[11][r]);
        *(float4*)(g0 + 12) = make_float4(acc0[12][r], acc0[13][r], acc0[14][r], acc0[15][r]);
        float* g1 = g0 + 16*1024;
        *(float4*)(g1)      = make_float4(acc1[0][r],  acc1[1][r],  acc1[2][r],  acc1[3][r]);
        *(float4*)(g1 + 4)  = make_float4(acc1[4][r],  acc1[5][r],  acc1[6][r],  acc1[7][r]);
        *(float4*)(g1 + 8)  = make_float4(acc1[8][r],  acc1[9][r],  acc1[10][r], acc1[11][r]);
        *(float4*)(g1 + 12) = make_float4(acc1[12][r], acc1[13][r], acc1[14][r], acc1[15][r]);
    }
}

// ================= fp32 last-resort fallback (verified R3) ===================
__global__ __launch_bounds__(256, 1) void gb_fused_f32(
    const float* __restrict__ x, const float* __restrict__ ref,
    const float* __restrict__ w1, const float* __restrict__ b1,
    const float* __restrict__ w2, const float* __restrict__ b2,
    float* __restrict__ out)
{
    __shared__ float lds[16384];
    __shared__ float lrefs[8];
    const int t = threadIdx.x;
    const int p0 = blockIdx.x * 8;
    {
        const float4* xg = reinterpret_cast<const float4*>(x) + (size_t)p0 * 256;
        float4* xl = reinterpret_cast<float4*>(lds);
        #pragma unroll
        for (int r = 0; r < 8; ++r) xl[r*256 + t] = xg[r*256 + t];
        if (t < 8) lrefs[t] = ref[(p0 + t)*16 + 15];
    }
    __syncthreads();
    const int c    = t & 127;
    const int half = t >> 7;
    const int ca   = (c < 64) ? c : (c + 64);
    const int cb   = ca + 64;
    float acc[4][2][16];
    #pragma unroll
    for (int q = 0; q < 4; ++q)
        #pragma unroll
        for (int s = 0; s < 2; ++s)
            #pragma unroll
            for (int j = 0; j < 16; ++j) acc[q][s][j] = 0.f;
    for (int i = 0; i < 64; ++i) {
        float wa[9], wb[9];
        #pragma unroll
        for (int r = 0; r < 9; ++r) { wa[r] = w1[(ca*64+i)*9 + r]; wb[r] = w1[(cb*64+i)*9 + r]; }
        #pragma unroll
        for (int q = 0; q < 4; ++q) {
            const float* xv = lds + (half*4 + q)*1024 + i*16;
            float xr[16];
            #pragma unroll
            for (int j4 = 0; j4 < 4; ++j4) {
                const float4 v = *reinterpret_cast<const float4*>(xv + 4*j4);
                xr[4*j4+0]=v.x; xr[4*j4+1]=v.y; xr[4*j4+2]=v.z; xr[4*j4+3]=v.w;
            }
            #pragma unroll
            for (int e = 0; e < 8; ++e) {
                const int ge = GE[e];
                const float xe = xr[2*e], xo = xr[2*e+1];
                acc[q][0][2*e]   += wa[ge]   * xe;
                acc[q][0][2*e+1] += wa[ge+1] * xo;
                acc[q][0][2*e+1] += wa[ge+5] * xe;
                acc[q][1][2*e]   += wb[ge]   * xe;
                acc[q][1][2*e+1] += wb[ge+1] * xo;
                acc[q][1][2*e+1] += wb[ge+5] * xe;
            }
        }
    }
    {
        const float ba = b1[ca], bb = b1[cb];
        #pragma unroll
        for (int q = 0; q < 4; ++q) { acc[q][0][0] += ba; acc[q][1][0] += bb; }
    }
    __syncthreads();
    #pragma unroll
    for (int q = 0; q < 4; ++q) {
        float prod[16];
        #pragma unroll
        for (int j = 0; j < 16; ++j) prod[j] = 0.f;
        if (c < 64) {
            #pragma unroll
            for (int A = 0; A < 16; ++A)
                #pragma unroll
                for (int B = 0; B < 16; ++B)
                    if (TB.gp[A][B] != 0.f)
                        prod[A ^ B] += TB.gp[A][B] * acc[q][0][A] * acc[q][1][B];
        } else {
            #pragma unroll
            for (int A = 0; A < 16; ++A)
                #pragma unroll
                for (int B = 0; B < 16; ++B)
                    if (TB.jn[A][B] != 0.f)
                        prod[A & B] += TB.jn[A][B] * acc[q][0][A] * acc[q][1][B];
            const float rp = lrefs[half*4 + q];
            #pragma unroll
            for (int j = 0; j < 16; ++j) prod[j] *= rp;
        }
        const int pos = half*4 + q;
        #pragma unroll
        for (int j4 = 0; j4 < 4; ++j4)
            *reinterpret_cast<float4*>(&lds[(pos*4 + j4)*512 + c*4]) =
                make_float4(prod[4*j4], prod[4*j4+1], prod[4*j4+2], prod[4*j4+3]);
    }
    __syncthreads();
    const int o    = t & 63;
    const int slot = t >> 6;
    float oacc[2][16];
    #pragma unroll
    for (int e2 = 0; e2 < 2; ++e2)
        #pragma unroll
        for (int j = 0; j < 16; ++j) oacc[e2][j] = 0.f;
    for (int i = 0; i < 128; ++i) {
        float wv[9];
        #pragma unroll
        for (int r = 0; r < 9; ++r) wv[r] = w2[(o*128+i)*9 + r];
        #pragma unroll
        for (int e2 = 0; e2 < 2; ++e2) {
            const int pos = slot*2 + e2;
            float xr[16];
            #pragma unroll
            for (int j4 = 0; j4 < 4; ++j4) {
                const float4 v = *reinterpret_cast<const float4*>(&lds[(pos*4 + j4)*512 + i*4]);
                xr[4*j4+0]=v.x; xr[4*j4+1]=v.y; xr[4*j4+2]=v.z; xr[4*j4+3]=v.w;
            }
            #pragma unroll
            for (int e = 0; e < 8; ++e) {
                const int ge = GE[e];
                oacc[e2][2*e]   += wv[ge]   * xr[2*e];
                oacc[e2][2*e+1] += wv[ge+1] * xr[2*e+1];
                oacc[e2][2*e+1] += wv[ge+5] * xr[2*e];
            }
        }
    }
    {
        const float bo = b2[o];
        #pragma unroll
        for (int e2 = 0; e2 < 2; ++e2) {
            oacc[e2][0] += bo;
            const int pos = p0 + slot*2 + e2;
            float* og = out + (size_t)pos*1024 + o*16;
            #pragma unroll
            for (int j4 = 0; j4 < 4; ++j4)
                *reinterpret_cast<float4*>(og + 4*j4) =
                    make_float4(oacc[e2][4*j4], oacc[e2][4*j4+1],
                                oacc[e2][4*j4+2], oacc[e2][4*j4+3]);
        }
    }
}

extern "C" void kernel_launch(void* const* d_in, const int* in_sizes, int n_in,
                              void* d_out, int out_size, void* d_ws, size_t ws_size,
                              hipStream_t stream)
{
    const float* x  = (const float*)d_in[0];
    const float* rf = (const float*)d_in[1];
    const float* w1 = (const float*)d_in[2];
    const float* b1 = (const float*)d_in[3];
    const float* w2 = (const float*)d_in[4];
    const float* b2 = (const float*)d_in[5];
    float* out = (float*)d_out;

    const size_t need = O2_BYTES + (size_t)(W1F_ELEMS + W2F_ELEMS)*2;
    if (ws_size >= need) {
        unsigned short* o2G = (unsigned short*)d_ws;
        unsigned short* w1f = (unsigned short*)((char*)d_ws + O2_BYTES);
        unsigned short* w2f = w1f + W1F_ELEMS;
        prep_w<<<(W1F_ELEMS + W2F_ELEMS + 255)/256, 256, 0, stream>>>(w1, w2, w1f, w2f);
        gbA<<<1024, 256, 0, stream>>>(x, rf, b1, w1f, o2G);
        gbB<<<512, 256, 0, stream>>>(o2G, b2, w2f, out);
    } else {
        gb_fused_f32<<<2048, 256, 0, stream>>>(x, rf, w1, b1, w2, b2, out);
    }
}